// Round 4
// baseline (391.357 us; speedup 1.0000x reference)
//
#include <hip/hip_runtime.h>

// GWRouter: x = mean(wm_state [4,4096,2048] f32); sim[e] = -(proto[e]-x)^2;
// probs = softmax(sim); top-2; mask; EMA usage update; balance loss.
// Outputs flat f32: mask[0:16), probs[16:32), balance_loss[32],
// new_usage_ema[33:49), topk_idx[49:51).
//
// R2 lesson: nontemporal load (L3 bypass) + 1-load-in-flight -> 810 GB/s.
// R3 lesson: per-block contiguous 64KiB chunks -> aligned bases cluster on a
//   few HBM channels -> 427 GB/s. Grid-stride is channel-uniform; keep it.
// R4: grid-stride + fully unrolled 8 independent plain float4 loads/thread.

#define NUM_EXPERTS 16
#define RED_BLOCKS 4096
#define RED_THREADS 256
#define ITERS 8   // 4096*256 threads * 8 float4 * 4 = 33,554,432 floats exactly

typedef float f32x4 __attribute__((ext_vector_type(4)));

__global__ __launch_bounds__(RED_THREADS)
void gw_router_fused(const f32x4* __restrict__ x4, int n4,
                     const float* __restrict__ prototypes,
                     const float* __restrict__ usage_ema,
                     float* __restrict__ out,
                     double* __restrict__ partials,
                     unsigned int* __restrict__ counter,
                     long long n_total) {
    __shared__ double sdata[RED_THREADS / 64];
    __shared__ int s_is_last;

    const int tid = blockIdx.x * RED_THREADS + threadIdx.x;
    const int stride = RED_BLOCKS * RED_THREADS;  // 1,048,576 float4s

    f32x4 s0 = {0.f, 0.f, 0.f, 0.f};
    f32x4 s1 = {0.f, 0.f, 0.f, 0.f};
    f32x4 s2 = {0.f, 0.f, 0.f, 0.f};
    f32x4 s3 = {0.f, 0.f, 0.f, 0.f};

    if ((size_t)tid + (size_t)(ITERS - 1) * stride < (size_t)n4 &&
        n4 == ITERS * stride) {
        // fast path (exact for the fixed 8M-float4 shape): 8 independent
        // coalesced grid-stride loads, all issued before any accumulate.
        f32x4 v0 = x4[tid + 0 * stride];
        f32x4 v1 = x4[tid + 1 * stride];
        f32x4 v2 = x4[tid + 2 * stride];
        f32x4 v3 = x4[tid + 3 * stride];
        f32x4 v4 = x4[tid + 4 * stride];
        f32x4 v5 = x4[tid + 5 * stride];
        f32x4 v6 = x4[tid + 6 * stride];
        f32x4 v7 = x4[tid + 7 * stride];
        s0 = v0 + v4;
        s1 = v1 + v5;
        s2 = v2 + v6;
        s3 = v3 + v7;
    } else {
        for (int i = tid; i < n4; i += stride) s0 += x4[i];
    }

    f32x4 sv = (s0 + s1) + (s2 + s3);
    double acc = ((double)sv.x + (double)sv.y) + ((double)sv.z + (double)sv.w);
    #pragma unroll
    for (int off = 32; off > 0; off >>= 1)
        acc += __shfl_down(acc, off, 64);

    const int lane = threadIdx.x & 63;
    const int wave = threadIdx.x >> 6;
    if (lane == 0) sdata[wave] = acc;
    __syncthreads();

    if (threadIdx.x == 0) {
        double s = sdata[0] + sdata[1] + sdata[2] + sdata[3];
        partials[blockIdx.x] = s;
        // ACQ_REL RMW at agent scope: releases our partial store; the last
        // arriver's acquire synchronizes with every earlier release.
        unsigned prev = __hip_atomic_fetch_add(counter, 1u, __ATOMIC_ACQ_REL,
                                               __HIP_MEMORY_SCOPE_AGENT);
        s_is_last = (prev == (unsigned)(gridDim.x - 1)) ? 1 : 0;
    }
    __syncthreads();
    if (!s_is_last) return;

    // ---- last block: final reduction over partials ----
    double facc = 0.0;
    for (int p = threadIdx.x; p < RED_BLOCKS; p += RED_THREADS)
        facc += __hip_atomic_load(&partials[p], __ATOMIC_RELAXED,
                                  __HIP_MEMORY_SCOPE_AGENT);
    #pragma unroll
    for (int off = 32; off > 0; off >>= 1)
        facc += __shfl_down(facc, off, 64);
    if (lane == 0) sdata[wave] = facc;
    __syncthreads();

    if (threadIdx.x == 0) {
        const double total = sdata[0] + sdata[1] + sdata[2] + sdata[3];
        const float x = (float)(total / (double)n_total);

        float sim[NUM_EXPERTS];
        float m = -1e30f;
        #pragma unroll
        for (int e = 0; e < NUM_EXPERTS; ++e) {
            float d = prototypes[e] - x;
            sim[e] = -d * d;
            m = fmaxf(m, sim[e]);
        }
        float probs[NUM_EXPERTS];
        float s = 0.0f;
        #pragma unroll
        for (int e = 0; e < NUM_EXPERTS; ++e) {
            probs[e] = expf(sim[e] - m);
            s += probs[e];
        }
        const float inv_s = 1.0f / s;
        #pragma unroll
        for (int e = 0; e < NUM_EXPERTS; ++e) probs[e] *= inv_s;

        // top-2, lowest-index tie-break (matches jax.lax.top_k)
        int i0 = 0;
        #pragma unroll
        for (int e = 1; e < NUM_EXPERTS; ++e)
            if (probs[e] > probs[i0]) i0 = e;
        int i1 = -1;
        #pragma unroll
        for (int e = 0; e < NUM_EXPERTS; ++e) {
            if (e == i0) continue;
            if (i1 < 0 || probs[e] > probs[i1]) i1 = e;
        }

        const float alpha = 1.0f / 1000.0f;
        const float target = 1.0f / (float)NUM_EXPERTS;
        float bal = 0.0f;
        #pragma unroll
        for (int e = 0; e < NUM_EXPERTS; ++e) {
            float mk = (e == i0 || e == i1) ? 1.0f : 0.0f;
            float ne = (1.0f - alpha) * usage_ema[e] + alpha * mk;
            out[e]      = mk;       // mask
            out[16 + e] = probs[e]; // probs
            out[33 + e] = ne;       // new_usage_ema
            float dlt = ne - target;
            bal += dlt * dlt;
        }
        out[32] = (bal / (float)NUM_EXPERTS) * 1e-3f; // balance_loss
        out[49] = (float)i0;                          // topk_idx
        out[50] = (float)i1;
    }
}

extern "C" void kernel_launch(void* const* d_in, const int* in_sizes, int n_in,
                              void* d_out, int out_size, void* d_ws, size_t ws_size,
                              hipStream_t stream) {
    const f32x4* wm_state   = (const f32x4*)d_in[0];
    const float* prototypes = (const float*)d_in[1];
    const float* usage_ema  = (const float*)d_in[2];
    float* out = (float*)d_out;

    const long long n_total = (long long)in_sizes[0];
    const int n4 = (int)(n_total / 4);

    // d_ws layout: [0, 32 KiB) partials (4096 doubles), [32 KiB, +4) counter
    double* partials = (double*)d_ws;
    unsigned int* counter = (unsigned int*)((char*)d_ws + RED_BLOCKS * sizeof(double));

    hipMemsetAsync(counter, 0, sizeof(unsigned int), stream);
    gw_router_fused<<<RED_BLOCKS, RED_THREADS, 0, stream>>>(
        wm_state, n4, prototypes, usage_ema, out, partials, counter, n_total);
}

// Round 5
// 204.171 us; speedup vs baseline: 1.9168x; 1.9168x over previous
//
#include <hip/hip_runtime.h>

// GWRouter: x = mean(wm_state [4,4096,2048] f32); sim[e] = -(proto[e]-x)^2;
// probs = softmax(sim); top-2; mask; EMA usage update; balance loss.
// Outputs flat f32: mask[0:16), probs[16:32), balance_loss[32],
// new_usage_ema[33:49), topk_idx[49:51).
//
// Lessons: R2 nontemporal (L3 bypass) -> 810 GB/s. R3 contiguous per-block
// chunks -> channel clustering -> 427 GB/s. R4 showed time ~ 65ns * #blocks:
// the per-block agent-scope ACQ_REL fetch_add (release = vmcnt drain + L2
// writeback at the coherence point) serialized the whole dispatch. So: NO
// global atomics — two kernels, stream order gives coherence. MLP forced
// with sched_barrier(0): all 16 loads issued before any accumulate.

#define NUM_EXPERTS 16
#define RED_BLOCKS 2048
#define RED_THREADS 256
#define ITERS 16   // 2048*256 threads * 16 float4 * 4 = 33,554,432 floats

typedef float f32x4 __attribute__((ext_vector_type(4)));

__global__ __launch_bounds__(RED_THREADS)
void gw_reduce(const f32x4* __restrict__ x4, int n4,
               double* __restrict__ partials) {
    __shared__ double sdata[RED_THREADS / 64];

    const int tid = blockIdx.x * RED_THREADS + threadIdx.x;
    const int stride = RED_BLOCKS * RED_THREADS;  // 524,288 float4s

    f32x4 s0 = {0.f, 0.f, 0.f, 0.f};
    f32x4 s1 = {0.f, 0.f, 0.f, 0.f};
    f32x4 s2 = {0.f, 0.f, 0.f, 0.f};
    f32x4 s3 = {0.f, 0.f, 0.f, 0.f};

    if (n4 == ITERS * stride) {
        // Fast path (always taken for the fixed shape). Issue ALL 16 loads,
        // then a scheduling fence so the compiler cannot sink loads into
        // their uses (R4: it did, VGPR=20, 2 loads in flight, 260 GB/s).
        f32x4 v0  = x4[tid +  0 * stride];
        f32x4 v1  = x4[tid +  1 * stride];
        f32x4 v2  = x4[tid +  2 * stride];
        f32x4 v3  = x4[tid +  3 * stride];
        f32x4 v4  = x4[tid +  4 * stride];
        f32x4 v5  = x4[tid +  5 * stride];
        f32x4 v6  = x4[tid +  6 * stride];
        f32x4 v7  = x4[tid +  7 * stride];
        f32x4 v8  = x4[tid +  8 * stride];
        f32x4 v9  = x4[tid +  9 * stride];
        f32x4 v10 = x4[tid + 10 * stride];
        f32x4 v11 = x4[tid + 11 * stride];
        f32x4 v12 = x4[tid + 12 * stride];
        f32x4 v13 = x4[tid + 13 * stride];
        f32x4 v14 = x4[tid + 14 * stride];
        f32x4 v15 = x4[tid + 15 * stride];
        __builtin_amdgcn_sched_barrier(0);
        s0 = (v0 + v4) + (v8  + v12);
        s1 = (v1 + v5) + (v9  + v13);
        s2 = (v2 + v6) + (v10 + v14);
        s3 = (v3 + v7) + (v11 + v15);
    } else {
        for (int i = tid; i < n4; i += stride) s0 += x4[i];
    }

    f32x4 sv = (s0 + s1) + (s2 + s3);
    double acc = ((double)sv.x + (double)sv.y) + ((double)sv.z + (double)sv.w);
    #pragma unroll
    for (int off = 32; off > 0; off >>= 1)
        acc += __shfl_down(acc, off, 64);

    const int lane = threadIdx.x & 63;
    const int wave = threadIdx.x >> 6;
    if (lane == 0) sdata[wave] = acc;
    __syncthreads();
    if (threadIdx.x == 0)
        partials[blockIdx.x] = sdata[0] + sdata[1] + sdata[2] + sdata[3];
}

__global__ __launch_bounds__(RED_THREADS)
void gw_finalize(const double* __restrict__ partials,
                 const float* __restrict__ prototypes,
                 const float* __restrict__ usage_ema,
                 float* __restrict__ out,
                 long long n_total) {
    __shared__ double sdata[RED_THREADS / 64];

    double facc = 0.0;
    #pragma unroll
    for (int k = 0; k < RED_BLOCKS / RED_THREADS; ++k)
        facc += partials[threadIdx.x + k * RED_THREADS];
    #pragma unroll
    for (int off = 32; off > 0; off >>= 1)
        facc += __shfl_down(facc, off, 64);

    const int lane = threadIdx.x & 63;
    const int wave = threadIdx.x >> 6;
    if (lane == 0) sdata[wave] = facc;
    __syncthreads();

    if (threadIdx.x == 0) {
        const double total = sdata[0] + sdata[1] + sdata[2] + sdata[3];
        const float x = (float)(total / (double)n_total);

        float sim[NUM_EXPERTS];
        float m = -1e30f;
        #pragma unroll
        for (int e = 0; e < NUM_EXPERTS; ++e) {
            float d = prototypes[e] - x;
            sim[e] = -d * d;
            m = fmaxf(m, sim[e]);
        }
        float probs[NUM_EXPERTS];
        float s = 0.0f;
        #pragma unroll
        for (int e = 0; e < NUM_EXPERTS; ++e) {
            probs[e] = expf(sim[e] - m);
            s += probs[e];
        }
        const float inv_s = 1.0f / s;
        #pragma unroll
        for (int e = 0; e < NUM_EXPERTS; ++e) probs[e] *= inv_s;

        // top-2, lowest-index tie-break (matches jax.lax.top_k)
        int i0 = 0;
        #pragma unroll
        for (int e = 1; e < NUM_EXPERTS; ++e)
            if (probs[e] > probs[i0]) i0 = e;
        int i1 = -1;
        #pragma unroll
        for (int e = 0; e < NUM_EXPERTS; ++e) {
            if (e == i0) continue;
            if (i1 < 0 || probs[e] > probs[i1]) i1 = e;
        }

        const float alpha = 1.0f / 1000.0f;
        const float target = 1.0f / (float)NUM_EXPERTS;
        float bal = 0.0f;
        #pragma unroll
        for (int e = 0; e < NUM_EXPERTS; ++e) {
            float mk = (e == i0 || e == i1) ? 1.0f : 0.0f;
            float ne = (1.0f - alpha) * usage_ema[e] + alpha * mk;
            out[e]      = mk;       // mask
            out[16 + e] = probs[e]; // probs
            out[33 + e] = ne;       // new_usage_ema
            float dlt = ne - target;
            bal += dlt * dlt;
        }
        out[32] = (bal / (float)NUM_EXPERTS) * 1e-3f; // balance_loss
        out[49] = (float)i0;                          // topk_idx
        out[50] = (float)i1;
    }
}

extern "C" void kernel_launch(void* const* d_in, const int* in_sizes, int n_in,
                              void* d_out, int out_size, void* d_ws, size_t ws_size,
                              hipStream_t stream) {
    const f32x4* wm_state   = (const f32x4*)d_in[0];
    const float* prototypes = (const float*)d_in[1];
    const float* usage_ema  = (const float*)d_in[2];
    float* out = (float*)d_out;

    const long long n_total = (long long)in_sizes[0];
    const int n4 = (int)(n_total / 4);

    double* partials = (double*)d_ws;  // 2048 doubles = 16 KiB

    gw_reduce<<<RED_BLOCKS, RED_THREADS, 0, stream>>>(wm_state, n4, partials);
    gw_finalize<<<1, RED_THREADS, 0, stream>>>(partials, prototypes, usage_ema,
                                               out, n_total);
}

// Round 6
// 201.834 us; speedup vs baseline: 1.9390x; 1.0116x over previous
//
#include <hip/hip_runtime.h>

// GWRouter: x = mean(wm_state [4,4096,2048] f32); sim[e] = -(proto[e]-x)^2;
// probs = softmax(sim); top-2; mask; EMA usage update; balance loss.
// Outputs flat f32: mask[0:16), probs[16:32), balance_loss[32],
// new_usage_ema[33:49), topk_idx[49:51).
//
// Evidence so far: atomics-free two-kernel structure is best (R1/R5 ~203);
// nontemporal kills L3 hits (R2); contiguous per-block chunks cluster HBM
// channels (R3); single-line agent-scope fetch_add serializes blocks (R4).
// R6: explicit 4-stage software pipeline in the reduce loop — >=4 loads in
// flight by dataflow (independent of scheduler/regalloc decisions), f32x4
// accumulate in-loop, f64 conversion once at the end.

#define NUM_EXPERTS 16
#define RED_BLOCKS 2048
#define RED_THREADS 256
#define ITERS 16   // 2048*256 threads * 16 float4 * 4 = 33,554,432 floats

typedef float f32x4 __attribute__((ext_vector_type(4)));

__global__ __launch_bounds__(RED_THREADS)
void gw_reduce(const f32x4* __restrict__ x4, int n4,
               double* __restrict__ partials) {
    __shared__ double sdata[RED_THREADS / 64];

    const int tid = blockIdx.x * RED_THREADS + threadIdx.x;
    const int stride = RED_BLOCKS * RED_THREADS;  // 524,288 float4s

    f32x4 a0 = {0.f, 0.f, 0.f, 0.f};
    f32x4 a1 = {0.f, 0.f, 0.f, 0.f};
    f32x4 a2 = {0.f, 0.f, 0.f, 0.f};
    f32x4 a3 = {0.f, 0.f, 0.f, 0.f};

    if (n4 == ITERS * stride) {
        // 4-stage software pipeline: issue next 4 loads, then consume the
        // previous 4. Dataflow guarantees 4-8 loads in flight at all times.
        f32x4 c0 = x4[tid + 0 * stride];
        f32x4 c1 = x4[tid + 1 * stride];
        f32x4 c2 = x4[tid + 2 * stride];
        f32x4 c3 = x4[tid + 3 * stride];
        #pragma unroll
        for (int k = 4; k < ITERS; k += 4) {
            f32x4 n0 = x4[tid + (k + 0) * stride];
            f32x4 n1 = x4[tid + (k + 1) * stride];
            f32x4 n2 = x4[tid + (k + 2) * stride];
            f32x4 n3 = x4[tid + (k + 3) * stride];
            a0 += c0; a1 += c1; a2 += c2; a3 += c3;
            c0 = n0; c1 = n1; c2 = n2; c3 = n3;
        }
        a0 += c0; a1 += c1; a2 += c2; a3 += c3;
    } else {
        for (int i = tid; i < n4; i += stride) a0 += x4[i];
    }

    f32x4 sv = (a0 + a1) + (a2 + a3);
    double acc = ((double)sv.x + (double)sv.y) + ((double)sv.z + (double)sv.w);
    #pragma unroll
    for (int off = 32; off > 0; off >>= 1)
        acc += __shfl_down(acc, off, 64);

    const int lane = threadIdx.x & 63;
    const int wave = threadIdx.x >> 6;
    if (lane == 0) sdata[wave] = acc;
    __syncthreads();
    if (threadIdx.x == 0)
        partials[blockIdx.x] = sdata[0] + sdata[1] + sdata[2] + sdata[3];
}

__global__ __launch_bounds__(RED_THREADS)
void gw_finalize(const double* __restrict__ partials,
                 const float* __restrict__ prototypes,
                 const float* __restrict__ usage_ema,
                 float* __restrict__ out,
                 long long n_total) {
    __shared__ double sdata[RED_THREADS / 64];

    double facc = 0.0;
    #pragma unroll
    for (int k = 0; k < RED_BLOCKS / RED_THREADS; ++k)
        facc += partials[threadIdx.x + k * RED_THREADS];
    #pragma unroll
    for (int off = 32; off > 0; off >>= 1)
        facc += __shfl_down(facc, off, 64);

    const int lane = threadIdx.x & 63;
    const int wave = threadIdx.x >> 6;
    if (lane == 0) sdata[wave] = facc;
    __syncthreads();

    if (threadIdx.x == 0) {
        const double total = sdata[0] + sdata[1] + sdata[2] + sdata[3];
        const float x = (float)(total / (double)n_total);

        float sim[NUM_EXPERTS];
        float m = -1e30f;
        #pragma unroll
        for (int e = 0; e < NUM_EXPERTS; ++e) {
            float d = prototypes[e] - x;
            sim[e] = -d * d;
            m = fmaxf(m, sim[e]);
        }
        float probs[NUM_EXPERTS];
        float s = 0.0f;
        #pragma unroll
        for (int e = 0; e < NUM_EXPERTS; ++e) {
            probs[e] = expf(sim[e] - m);
            s += probs[e];
        }
        const float inv_s = 1.0f / s;
        #pragma unroll
        for (int e = 0; e < NUM_EXPERTS; ++e) probs[e] *= inv_s;

        // top-2, lowest-index tie-break (matches jax.lax.top_k)
        int i0 = 0;
        #pragma unroll
        for (int e = 1; e < NUM_EXPERTS; ++e)
            if (probs[e] > probs[i0]) i0 = e;
        int i1 = -1;
        #pragma unroll
        for (int e = 0; e < NUM_EXPERTS; ++e) {
            if (e == i0) continue;
            if (i1 < 0 || probs[e] > probs[i1]) i1 = e;
        }

        const float alpha = 1.0f / 1000.0f;
        const float target = 1.0f / (float)NUM_EXPERTS;
        float bal = 0.0f;
        #pragma unroll
        for (int e = 0; e < NUM_EXPERTS; ++e) {
            float mk = (e == i0 || e == i1) ? 1.0f : 0.0f;
            float ne = (1.0f - alpha) * usage_ema[e] + alpha * mk;
            out[e]      = mk;       // mask
            out[16 + e] = probs[e]; // probs
            out[33 + e] = ne;       // new_usage_ema
            float dlt = ne - target;
            bal += dlt * dlt;
        }
        out[32] = (bal / (float)NUM_EXPERTS) * 1e-3f; // balance_loss
        out[49] = (float)i0;                          // topk_idx
        out[50] = (float)i1;
    }
}

extern "C" void kernel_launch(void* const* d_in, const int* in_sizes, int n_in,
                              void* d_out, int out_size, void* d_ws, size_t ws_size,
                              hipStream_t stream) {
    const f32x4* wm_state   = (const f32x4*)d_in[0];
    const float* prototypes = (const float*)d_in[1];
    const float* usage_ema  = (const float*)d_in[2];
    float* out = (float*)d_out;

    const long long n_total = (long long)in_sizes[0];
    const int n4 = (int)(n_total / 4);

    double* partials = (double*)d_ws;  // 2048 doubles = 16 KiB

    gw_reduce<<<RED_BLOCKS, RED_THREADS, 0, stream>>>(wm_state, n4, partials);
    gw_finalize<<<1, RED_THREADS, 0, stream>>>(partials, prototypes, usage_ema,
                                               out, n_total);
}